// Round 4
// baseline (2652.444 us; speedup 1.0000x reference)
//
#include <hip/hip_runtime.h>
#include <cstdint>
#include <cstddef>

// CustomLSTM: B=64, S=512, I=1024, H=1024.
//   K1 : W fp32 -> bf16, B-fragment swizzle.
//   K1b: x fp32 -> bf16, A-fragment swizzle (Xsw) for global_load_lds staging.
//   K2 : xW = x@W + bias, 128x128 bf16 MFMA tiles, gload_lds width=16.
//   K3 : persistent scan, 256 wgs, ONE barrier per step, TAG-IN-DATA sync
//        (h stored as u32 = bf16<<16 | (t+1); consumer loads ARE the poll).
//        Round-4 change: the poll's vmcnt(0) retires IN ORDER, so any slow
//        vmem issued before it (HBM xW loads, HBM out store) inflates every
//        poll attempt. Now the out store + next-step xW prefetch are issued
//        RIGHT AFTER the poll succeeds — their latency hides under the
//        MFMA/barrier/reduce/elementwise phase — and the poll enters with
//        only the previous tagged LLC store outstanding.

typedef __attribute__((ext_vector_type(4))) float          f32x4;
typedef __attribute__((ext_vector_type(8))) short          s16x8;
typedef __attribute__((ext_vector_type(4))) unsigned int   u32x4;
typedef __attribute__((ext_vector_type(2))) unsigned short u16x2;
typedef unsigned long long u64;

#define S_LEN 512
#define HID   33554432   // 64*512*1024

__device__ __forceinline__ unsigned short f2bf(float f) {
  unsigned u = __builtin_bit_cast(unsigned, f);
  u += 0x7FFFu + ((u >> 16) & 1u);           // round-to-nearest-even
  return (unsigned short)(u >> 16);
}
__device__ __forceinline__ float bf2f(unsigned short h) {
  unsigned u = ((unsigned)h) << 16;
  return __builtin_bit_cast(float, u);
}
__device__ __forceinline__ float sigm(float x) {
  return __fdividef(1.f, 1.f + __expf(-x));
}
__device__ __forceinline__ float tanh_(float x) {
  return 1.f - __fdividef(2.f, 1.f + __expf(2.f * x));
}
__device__ __forceinline__ void gload16(const void* g, void* l) {
  __builtin_amdgcn_global_load_lds(
      (const __attribute__((address_space(1))) unsigned int*)g,
      (__attribute__((address_space(3))) unsigned int*)l, 16, 0, 0);
}

// ---------------- K1: W fp32 -> bf16, B-fragment swizzle ----------------
// W_sw layout: [kb=K/32][nb=N/128][ksub=4][col=128][i=8]  (k = kb*32+ksub*8+i)
__global__ __launch_bounds__(256) void k_convW(const float* __restrict__ W,
                                               unsigned short* __restrict__ Wsw) {
  int idx = blockIdx.x * 256 + threadIdx.x;   // 0 .. 4194303
  int k = idx >> 12, c = idx & 4095;
  int kb = k >> 5, ksub = (k >> 3) & 3, i = k & 7;
  int nb = c >> 7, col = c & 127;
  Wsw[(size_t)(((kb * 32 + nb) * 4 + ksub) * 128 + col) * 8 + i] = f2bf(W[idx]);
}

// ---------------- K1b: x fp32 -> bf16, A-fragment swizzle ----------------
__global__ __launch_bounds__(256) void k_convX(const float* __restrict__ x,
                                               unsigned short* __restrict__ Xsw) {
  int n = blockIdx.x * 256 + threadIdx.x;     // s16x8 units
  int row = n & 127;
  int t8 = n >> 7;
  int ksub = t8 & 3;
  int tile = t8 >> 2;
  int kb = tile & 31, mb = tile >> 5;
  const float* src = x + (size_t)(mb * 128 + row) * 1024 + kb * 32 + ksub * 8;
  f32x4 v0 = *(const f32x4*)src;
  f32x4 v1 = *(const f32x4*)(src + 4);
  s16x8 o;
  o[0] = (short)f2bf(v0[0]); o[1] = (short)f2bf(v0[1]);
  o[2] = (short)f2bf(v0[2]); o[3] = (short)f2bf(v0[3]);
  o[4] = (short)f2bf(v1[0]); o[5] = (short)f2bf(v1[1]);
  o[6] = (short)f2bf(v1[2]); o[7] = (short)f2bf(v1[3]);
  ((s16x8*)Xsw)[n] = o;
}

// ---------------- K2: xW = x @ W + bias (gload_lds staging) ----------------
__global__ __launch_bounds__(256) void k_gemm(const unsigned short* __restrict__ Xsw,
                                              const unsigned short* __restrict__ Wsw,
                                              const float* __restrict__ bias,
                                              unsigned short* __restrict__ xW) {
  __shared__ __align__(16) short As[4096];
  __shared__ __align__(16) short Bs[4096];
  const int nb = blockIdx.x;
  const int mb = blockIdx.y;
  const int tid = threadIdx.x;
  const int w = tid >> 6, lane = tid & 63;
  const int wm = w >> 1, wn = w & 1;
  const int quad = lane >> 4, l15 = lane & 15;

  f32x4 acc[4][4];
#pragma unroll
  for (int mt = 0; mt < 4; ++mt)
#pragma unroll
    for (int nt = 0; nt < 4; ++nt) acc[mt][nt] = (f32x4){0.f, 0.f, 0.f, 0.f};

  for (int kb = 0; kb < 32; ++kb) {
    const u32x4* ag = (const u32x4*)Xsw + ((size_t)(mb * 32 + kb)) * 512 + w * 128 + lane;
    const u32x4* bgp = (const u32x4*)Wsw + ((size_t)(kb * 32 + nb)) * 512 + w * 128 + lane;
    char* al = (char*)As + w * 2048;          // wave-uniform LDS base
    char* bl = (char*)Bs + w * 2048;
    gload16(ag, al);
    gload16(ag + 64, al + 1024);
    gload16(bgp, bl);
    gload16(bgp + 64, bl + 1024);
    __syncthreads();

    s16x8 a[4], b[4];
#pragma unroll
    for (int mt = 0; mt < 4; ++mt)
      a[mt] = ((const s16x8*)As)[quad * 128 + wm * 64 + mt * 16 + l15];
#pragma unroll
    for (int nt = 0; nt < 4; ++nt)
      b[nt] = ((const s16x8*)Bs)[quad * 128 + wn * 64 + nt * 16 + l15];
#pragma unroll
    for (int mt = 0; mt < 4; ++mt)
#pragma unroll
      for (int nt = 0; nt < 4; ++nt)
        acc[mt][nt] =
            __builtin_amdgcn_mfma_f32_16x16x32_bf16(a[mt], b[nt], acc[mt][nt], 0, 0, 0);
    __syncthreads();
  }

#pragma unroll
  for (int mt = 0; mt < 4; ++mt) {
    const int gr0 = mb * 128 + wm * 64 + mt * 16 + quad * 4;
#pragma unroll
    for (int nt = 0; nt < 4; ++nt) {
      const int gc = nb * 128 + wn * 64 + nt * 16 + l15;
      const int g = gc >> 10, jg = gc & 1023;
      const float bb = bias[gc];
#pragma unroll
      for (int r2 = 0; r2 < 4; ++r2) {
        const int gr = gr0 + r2;
        const int bi = gr >> 9, s = gr & 511;   // row = b*512 + s
        xW[(size_t)((g * 512 + s) * 64 + bi) * 1024 + jg] = f2bf(acc[mt][nt][r2] + bb);
      }
    }
  }
}

// ---------------- K2-legacy (ws too small for Xsw) ----------------
__global__ __launch_bounds__(256) void k_gemm_legacy(const float* __restrict__ x,
                                                     const unsigned short* __restrict__ Wsw,
                                                     const float* __restrict__ bias,
                                                     unsigned short* __restrict__ xW) {
  __shared__ __align__(16) short As[4096];
  __shared__ __align__(16) short Bs[4096];
  const int nb = blockIdx.x;
  const int mb = blockIdx.y;
  const int tid = threadIdx.x;
  const int w = tid >> 6, lane = tid & 63;
  const int wm = w >> 1, wn = w & 1;
  const int quad = lane >> 4, l15 = lane & 15;

  f32x4 acc[4][4];
#pragma unroll
  for (int mt = 0; mt < 4; ++mt)
#pragma unroll
    for (int nt = 0; nt < 4; ++nt) acc[mt][nt] = (f32x4){0.f, 0.f, 0.f, 0.f};

  const int r = tid >> 1, half = tid & 1;
  const float* xrow = x + (size_t)(mb * 128 + r) * 1024 + half * 16;
  const u32x4* wsrc = (const u32x4*)Wsw;
  u32x4* bdst = (u32x4*)Bs;
  s16x8* asv = (s16x8*)As;

  for (int kb = 0; kb < 32; ++kb) {
    f32x4 v0 = *(const f32x4*)(xrow + kb * 32);
    f32x4 v1 = *(const f32x4*)(xrow + kb * 32 + 4);
    f32x4 v2 = *(const f32x4*)(xrow + kb * 32 + 8);
    f32x4 v3 = *(const f32x4*)(xrow + kb * 32 + 12);
    s16x8 s0, s1;
    s0[0] = (short)f2bf(v0[0]); s0[1] = (short)f2bf(v0[1]);
    s0[2] = (short)f2bf(v0[2]); s0[3] = (short)f2bf(v0[3]);
    s0[4] = (short)f2bf(v1[0]); s0[5] = (short)f2bf(v1[1]);
    s0[6] = (short)f2bf(v1[2]); s0[7] = (short)f2bf(v1[3]);
    s1[0] = (short)f2bf(v2[0]); s1[1] = (short)f2bf(v2[1]);
    s1[2] = (short)f2bf(v2[2]); s1[3] = (short)f2bf(v2[3]);
    s1[4] = (short)f2bf(v3[0]); s1[5] = (short)f2bf(v3[1]);
    s1[6] = (short)f2bf(v3[2]); s1[7] = (short)f2bf(v3[3]);
    asv[(half * 2 + 0) * 128 + r] = s0;
    asv[(half * 2 + 1) * 128 + r] = s1;
    const u32x4* bsrc = wsrc + (size_t)(kb * 32 + nb) * 512;
    bdst[tid] = bsrc[tid];
    bdst[tid + 256] = bsrc[tid + 256];
    __syncthreads();

    s16x8 a[4], b[4];
#pragma unroll
    for (int mt = 0; mt < 4; ++mt)
      a[mt] = ((const s16x8*)As)[quad * 128 + wm * 64 + mt * 16 + l15];
#pragma unroll
    for (int nt = 0; nt < 4; ++nt)
      b[nt] = ((const s16x8*)Bs)[quad * 128 + wn * 64 + nt * 16 + l15];
#pragma unroll
    for (int mt = 0; mt < 4; ++mt)
#pragma unroll
      for (int nt = 0; nt < 4; ++nt)
        acc[mt][nt] =
            __builtin_amdgcn_mfma_f32_16x16x32_bf16(a[mt], b[nt], acc[mt][nt], 0, 0, 0);
    __syncthreads();
  }

#pragma unroll
  for (int mt = 0; mt < 4; ++mt) {
    const int gr0 = mb * 128 + wm * 64 + mt * 16 + quad * 4;
#pragma unroll
    for (int nt = 0; nt < 4; ++nt) {
      const int gc = nb * 128 + wn * 64 + nt * 16 + l15;
      const int g = gc >> 10, jg = gc & 1023;
      const float bb = bias[gc];
#pragma unroll
      for (int r2 = 0; r2 < 4; ++r2) {
        const int gr = gr0 + r2;
        const int bi = gr >> 9, s = gr & 511;
        xW[(size_t)((g * 512 + s) * 64 + bi) * 1024 + jg] = f2bf(acc[mt][nt][r2] + bb);
      }
    }
  }
}

// ---------------- K3: persistent scan, tag-in-data sync ----------------
// hbuf (u32): [parity][mi=4][kbg=32][lane=64][i=8]; entry = bf16(h)<<16 | tag,
// tag = t+1 for h produced at step t (parity t&1). 65536 u32 per parity.
// Consumer at step t reads parity (t-1)&1 expecting tag == t. On that parity
// tags are provably <= t (a producer can only write tag t+2 there after ALL
// wgs of the mi-group stored tag t+1 — the closure through each wg's barrier
// bounds inter-wg skew), so min(tag)==t <=> all fresh. Double-buffer +
// exact-match makes overwrite safe; per-dword store visibility carries
// value+tag atomically: no fences, no flags, no producer drain.
//
// The load clause AND its s_waitcnt vmcnt(0) are ONE asm block with "=&v"
// early-clobber outputs. vmcnt retires IN ORDER, so all slow vmem (HBM out
// store, HBM xW prefetch) is issued right AFTER the poll and retires under
// the compute phase — the poll enters with only the tagged LLC store
// outstanding.
#define HLOAD(PAR)                                                             \
  {                                                                            \
    const unsigned* bp_ = hbuf + (size_t)(PAR)*65536 + hb_r_base;              \
    u64 a0_ = (u64)(uintptr_t)bp_;                                             \
    u64 a1_ = a0_ + 4096;                                                      \
    u64 a2_ = a0_ + 8192;                                                      \
    u64 a3_ = a0_ + 12288;                                                     \
    asm volatile("global_load_dwordx4 %0, %16, off sc0 sc1\n\t"                \
                 "global_load_dwordx4 %1, %16, off offset:16 sc0 sc1\n\t"      \
                 "global_load_dwordx4 %2, %16, off offset:2048 sc0 sc1\n\t"    \
                 "global_load_dwordx4 %3, %16, off offset:2064 sc0 sc1\n\t"    \
                 "global_load_dwordx4 %4, %17, off sc0 sc1\n\t"                \
                 "global_load_dwordx4 %5, %17, off offset:16 sc0 sc1\n\t"      \
                 "global_load_dwordx4 %6, %17, off offset:2048 sc0 sc1\n\t"    \
                 "global_load_dwordx4 %7, %17, off offset:2064 sc0 sc1\n\t"    \
                 "global_load_dwordx4 %8, %18, off sc0 sc1\n\t"                \
                 "global_load_dwordx4 %9, %18, off offset:16 sc0 sc1\n\t"      \
                 "global_load_dwordx4 %10, %18, off offset:2048 sc0 sc1\n\t"   \
                 "global_load_dwordx4 %11, %18, off offset:2064 sc0 sc1\n\t"   \
                 "global_load_dwordx4 %12, %19, off sc0 sc1\n\t"               \
                 "global_load_dwordx4 %13, %19, off offset:16 sc0 sc1\n\t"     \
                 "global_load_dwordx4 %14, %19, off offset:2048 sc0 sc1\n\t"   \
                 "global_load_dwordx4 %15, %19, off offset:2064 sc0 sc1\n\t"   \
                 "s_waitcnt vmcnt(0)"                                          \
                 : "=&v"(q[0]), "=&v"(q[1]), "=&v"(q[2]), "=&v"(q[3]),         \
                   "=&v"(q[4]), "=&v"(q[5]), "=&v"(q[6]), "=&v"(q[7]),         \
                   "=&v"(q[8]), "=&v"(q[9]), "=&v"(q[10]), "=&v"(q[11]),       \
                   "=&v"(q[12]), "=&v"(q[13]), "=&v"(q[14]), "=&v"(q[15])      \
                 : "v"(a0_), "v"(a1_), "v"(a2_), "v"(a3_)                      \
                 : "memory");                                                  \
  }

__global__ __launch_bounds__(256, 1) void k_scan(const float* __restrict__ U,
                                                 const unsigned short* __restrict__ xW,
                                                 unsigned* hbuf,
                                                 float* __restrict__ out) {
  __shared__ __align__(16) float P[10240];   // [par=2][w*4+g=16][j=16][b=20pad]

  const int wg = blockIdx.x;
  const int mi = wg >> 6, ni = wg & 63;
  const int tid = threadIdx.x;
  const int w = tid >> 6, lane = tid & 63;
  const int quad = lane >> 4, l15 = lane & 15;
  const int b_loc = tid >> 4, j_loc = tid & 15;

  // ---- load U fragments into registers (one-time) ----
  s16x8 uf[4][8];
  {
    const int cbase = ni * 16 + l15;
#pragma unroll
    for (int g = 0; g < 4; ++g) {
#pragma unroll
      for (int kb = 0; kb < 8; ++kb) {
        const int k0 = w * 256 + kb * 32 + quad * 8;
        s16x8 v;
#pragma unroll
        for (int i = 0; i < 8; ++i)
          v[i] = (short)f2bf(U[(size_t)(k0 + i) * 4096 + g * 1024 + cbase]);
        uf[g][kb] = v;
      }
    }
  }

  const int bg = mi * 16 + b_loc;             // global batch
  const int jg = ni * 16 + j_loc;             // global hidden unit
  const size_t hb_w_off =
      (size_t)((mi * 32 + (jg >> 5)) * 64 + ((jg >> 3) & 3) * 16 + b_loc) * 8 + (jg & 7);
  const size_t hb_r_base = (size_t)mi * 16384 + (size_t)w * 4096 + (size_t)lane * 8;
  float c = 0.f;
  float h_prev = 0.f;
  unsigned short xwv_cur[4], xwv_nxt[4];
#pragma unroll
  for (int g = 0; g < 4; ++g)                 // prologue: xW[t=0]
    xwv_cur[g] = xW[(size_t)((g * 512 + 0) * 64 + bg) * 1024 + jg];

  for (int t = 0; t < S_LEN; ++t) {
    float gate[4];
    const int par = (t & 1) * 16;
    if (t > 0) {
      u32x4 q[16];
      // load clause == poll: retry until every tag in the wave's slice == t.
      // Entering here only the tagged LLC store (and residual xW loads issued
      // one full compute-phase ago) are outstanding — cheap in-order retire.
      for (;;) {
        HLOAD((t & 1) ^ 1)
        u16x2 mn = (u16x2){0xFFFFu, 0xFFFFu};
#pragma unroll
        for (int i = 0; i < 16; ++i)
#pragma unroll
          for (int j = 0; j < 4; ++j)
            mn = __builtin_elementwise_min(mn, __builtin_bit_cast(u16x2, q[i][j]));
        if (!__any((int)((unsigned)mn[0] != (unsigned)t))) break;
      }

      // slow vmem issued NOW: retires under the MFMA/barrier/reduce phase,
      // never inside a poll. ("memory" clobber on HLOAD pins both sides.)
      out[(size_t)bg * (S_LEN * 1024) + (size_t)(t - 1) * 1024 + jg] = h_prev;
      if (t + 1 < S_LEN) {
#pragma unroll
        for (int g = 0; g < 4; ++g)
          xwv_nxt[g] = xW[(size_t)((g * 512 + t + 1) * 64 + bg) * 1024 + jg];
      }

      f32x4 acc[4];
#pragma unroll
      for (int g = 0; g < 4; ++g) acc[g] = (f32x4){0.f, 0.f, 0.f, 0.f};
#pragma unroll
      for (int kb = 0; kb < 8; ++kb) {
        u32x4 fw;
        fw[0] = __builtin_amdgcn_perm(q[2 * kb][1], q[2 * kb][0], 0x07060302u);
        fw[1] = __builtin_amdgcn_perm(q[2 * kb][3], q[2 * kb][2], 0x07060302u);
        fw[2] = __builtin_amdgcn_perm(q[2 * kb + 1][1], q[2 * kb + 1][0], 0x07060302u);
        fw[3] = __builtin_amdgcn_perm(q[2 * kb + 1][3], q[2 * kb + 1][2], 0x07060302u);
        s16x8 a = __builtin_bit_cast(s16x8, fw);
#pragma unroll
        for (int g = 0; g < 4; ++g)
          acc[g] = __builtin_amdgcn_mfma_f32_16x16x32_bf16(a, uf[g][kb], acc[g], 0, 0, 0);
      }
#pragma unroll
      for (int g = 0; g < 4; ++g) {
        float* dp = &P[(size_t)((par + w * 4 + g) * 16 + l15) * 20 + quad * 4];
        *(f32x4*)dp = acc[g];
      }
      __syncthreads();   // the ONLY barrier: P ready for cross-wave reduce
#pragma unroll
      for (int g = 0; g < 4; ++g) {
        float s = bf2f(xwv_cur[g]);
#pragma unroll
        for (int w2 = 0; w2 < 4; ++w2)
          s += P[(size_t)((par + w2 * 4 + g) * 16 + j_loc) * 20 + b_loc];
        gate[g] = s;
      }
    } else {
      // t == 0: no poll; prefetch xW[1] early (full step to cover HBM latency)
#pragma unroll
      for (int g = 0; g < 4; ++g)
        xwv_nxt[g] = xW[(size_t)((g * 512 + 1) * 64 + bg) * 1024 + jg];
#pragma unroll
      for (int g = 0; g < 4; ++g) gate[g] = bf2f(xwv_cur[g]);
    }

    const float it = sigm(gate[0]);
    const float ft = sigm(gate[1]);
    const float gt = tanh_(gate[2]);
    const float ot = sigm(gate[3]);
    c = ft * c + it * gt;
    const float h = ot * tanh_(c);

    // tagged h store (value+tag in one dword -> atomic visibility, no fence).
    // Ordering: issued AFTER the P-read (reduce) — certifies both "h_t ready"
    // and "my tile-(t-1) consumption done" to peers. Skipped at t=511 (dead).
    if (t + 1 < S_LEN) {
      const unsigned tagged = ((unsigned)f2bf(h) << 16) | (unsigned)(t + 1);
      __hip_atomic_store(hbuf + (size_t)(t & 1) * 65536 + hb_w_off, tagged,
                         __ATOMIC_RELAXED, __HIP_MEMORY_SCOPE_AGENT);
    }
    h_prev = h;
#pragma unroll
    for (int g = 0; g < 4; ++g) xwv_cur[g] = xwv_nxt[g];
  }

  // epilogue: flush step-511 output + final h/c
  out[(size_t)bg * (S_LEN * 1024) + (size_t)(S_LEN - 1) * 1024 + jg] = h_prev;
  out[HID + (size_t)bg * 1024 + jg] = h_prev;              // h_t
  out[HID + 65536 + (size_t)bg * 1024 + jg] = c;           // c_t
}

// ---------------- launch ----------------
extern "C" void kernel_launch(void* const* d_in, const int* in_sizes, int n_in,
                              void* d_out, int out_size, void* d_ws, size_t ws_size,
                              hipStream_t stream) {
  const float* x = (const float*)d_in[0];     // [64,512,1024]
  const float* W = (const float*)d_in[1];     // [1024,4096]
  const float* U = (const float*)d_in[2];     // [1024,4096]
  const float* bias = (const float*)d_in[3];  // [4096]
  float* out = (float*)d_out;
  char* ws = (char*)d_ws;

  // ws layout:
  unsigned* hbuf = (unsigned*)ws;                                    // 512 KB
  unsigned short* Wsw = (unsigned short*)(ws + 524288);              // 8 MB
  unsigned short* xW = (unsigned short*)(ws + 524288 + 8388608);     // 256 MB
  const size_t base = 524288 + 8388608 + 268435456;
  unsigned short* Xsw = (unsigned short*)(ws + base);                // 64 MB

  hipMemsetAsync(ws, 0, 524288, stream);   // zero hbuf (tag 0 everywhere)

  hipLaunchKernelGGL(k_convW, dim3(16384), dim3(256), 0, stream, W, Wsw);
  if (ws_size >= base + 67108864ULL) {
    hipLaunchKernelGGL(k_convX, dim3(16384), dim3(256), 0, stream, x, Xsw);
    hipLaunchKernelGGL(k_gemm, dim3(32, 256), dim3(256), 0, stream, Xsw, Wsw, bias, xW);
  } else {
    hipLaunchKernelGGL(k_gemm_legacy, dim3(32, 256), dim3(256), 0, stream, x, Wsw, bias,
                       xW);
  }
  hipLaunchKernelGGL(k_scan, dim3(256), dim3(256), 0, stream, U, xW, hbuf, out);
}

// Round 5
// 2342.556 us; speedup vs baseline: 1.1323x; 1.1323x over previous
//
#include <hip/hip_runtime.h>
#include <cstdint>
#include <cstddef>

// CustomLSTM: B=64, S=512, I=1024, H=1024.
//   K1 : W fp32 -> bf16, B-fragment swizzle.
//   K1b: x fp32 -> bf16, A-fragment swizzle (Xsw) for global_load_lds staging.
//   K2 : xW = x@W + bias, 128x128 bf16 MFMA tiles, gload_lds width=16.
//   K3 : persistent scan, 256 wgs, ONE barrier per step, TAG-IN-DATA sync
//        (h stored as u32 = bf16<<16 | (t+1); consumer loads ARE the poll).
//        Round-5: REVERT to round-3 schedule (xW prefetch at top + out store
//        at end — the slow vmem inside the first vmcnt(0) is a free backoff
//        that lets producer stores land; round-4's eager poll regressed).
//        NEW: selective per-group retry — the 16-load clause is split into
//        4 sub-clauses (one per 4KB address group = 4 producers); only stale
//        groups re-issue, cutting retry LLC traffic 4x. Issue blocks use
//        "=&v" early-clobber, the wait block binds all q regs "+v" with
//        vmcnt(0) (no counting) — the two round-2 failure modes are absent.

typedef __attribute__((ext_vector_type(4))) float          f32x4;
typedef __attribute__((ext_vector_type(8))) short          s16x8;
typedef __attribute__((ext_vector_type(4))) unsigned int   u32x4;
typedef __attribute__((ext_vector_type(2))) unsigned short u16x2;
typedef unsigned long long u64;

#define S_LEN 512
#define HID   33554432   // 64*512*1024

__device__ __forceinline__ unsigned short f2bf(float f) {
  unsigned u = __builtin_bit_cast(unsigned, f);
  u += 0x7FFFu + ((u >> 16) & 1u);           // round-to-nearest-even
  return (unsigned short)(u >> 16);
}
__device__ __forceinline__ float bf2f(unsigned short h) {
  unsigned u = ((unsigned)h) << 16;
  return __builtin_bit_cast(float, u);
}
__device__ __forceinline__ float sigm(float x) {
  return __fdividef(1.f, 1.f + __expf(-x));
}
__device__ __forceinline__ float tanh_(float x) {
  return 1.f - __fdividef(2.f, 1.f + __expf(2.f * x));
}
__device__ __forceinline__ void gload16(const void* g, void* l) {
  __builtin_amdgcn_global_load_lds(
      (const __attribute__((address_space(1))) unsigned int*)g,
      (__attribute__((address_space(3))) unsigned int*)l, 16, 0, 0);
}

// ---------------- K1: W fp32 -> bf16, B-fragment swizzle ----------------
// W_sw layout: [kb=K/32][nb=N/128][ksub=4][col=128][i=8]  (k = kb*32+ksub*8+i)
__global__ __launch_bounds__(256) void k_convW(const float* __restrict__ W,
                                               unsigned short* __restrict__ Wsw) {
  int idx = blockIdx.x * 256 + threadIdx.x;   // 0 .. 4194303
  int k = idx >> 12, c = idx & 4095;
  int kb = k >> 5, ksub = (k >> 3) & 3, i = k & 7;
  int nb = c >> 7, col = c & 127;
  Wsw[(size_t)(((kb * 32 + nb) * 4 + ksub) * 128 + col) * 8 + i] = f2bf(W[idx]);
}

// ---------------- K1b: x fp32 -> bf16, A-fragment swizzle ----------------
__global__ __launch_bounds__(256) void k_convX(const float* __restrict__ x,
                                               unsigned short* __restrict__ Xsw) {
  int n = blockIdx.x * 256 + threadIdx.x;     // s16x8 units
  int row = n & 127;
  int t8 = n >> 7;
  int ksub = t8 & 3;
  int tile = t8 >> 2;
  int kb = tile & 31, mb = tile >> 5;
  const float* src = x + (size_t)(mb * 128 + row) * 1024 + kb * 32 + ksub * 8;
  f32x4 v0 = *(const f32x4*)src;
  f32x4 v1 = *(const f32x4*)(src + 4);
  s16x8 o;
  o[0] = (short)f2bf(v0[0]); o[1] = (short)f2bf(v0[1]);
  o[2] = (short)f2bf(v0[2]); o[3] = (short)f2bf(v0[3]);
  o[4] = (short)f2bf(v1[0]); o[5] = (short)f2bf(v1[1]);
  o[6] = (short)f2bf(v1[2]); o[7] = (short)f2bf(v1[3]);
  ((s16x8*)Xsw)[n] = o;
}

// ---------------- K2: xW = x @ W + bias (gload_lds staging) ----------------
__global__ __launch_bounds__(256) void k_gemm(const unsigned short* __restrict__ Xsw,
                                              const unsigned short* __restrict__ Wsw,
                                              const float* __restrict__ bias,
                                              unsigned short* __restrict__ xW) {
  __shared__ __align__(16) short As[4096];
  __shared__ __align__(16) short Bs[4096];
  const int nb = blockIdx.x;
  const int mb = blockIdx.y;
  const int tid = threadIdx.x;
  const int w = tid >> 6, lane = tid & 63;
  const int wm = w >> 1, wn = w & 1;
  const int quad = lane >> 4, l15 = lane & 15;

  f32x4 acc[4][4];
#pragma unroll
  for (int mt = 0; mt < 4; ++mt)
#pragma unroll
    for (int nt = 0; nt < 4; ++nt) acc[mt][nt] = (f32x4){0.f, 0.f, 0.f, 0.f};

  for (int kb = 0; kb < 32; ++kb) {
    const u32x4* ag = (const u32x4*)Xsw + ((size_t)(mb * 32 + kb)) * 512 + w * 128 + lane;
    const u32x4* bgp = (const u32x4*)Wsw + ((size_t)(kb * 32 + nb)) * 512 + w * 128 + lane;
    char* al = (char*)As + w * 2048;          // wave-uniform LDS base
    char* bl = (char*)Bs + w * 2048;
    gload16(ag, al);
    gload16(ag + 64, al + 1024);
    gload16(bgp, bl);
    gload16(bgp + 64, bl + 1024);
    __syncthreads();

    s16x8 a[4], b[4];
#pragma unroll
    for (int mt = 0; mt < 4; ++mt)
      a[mt] = ((const s16x8*)As)[quad * 128 + wm * 64 + mt * 16 + l15];
#pragma unroll
    for (int nt = 0; nt < 4; ++nt)
      b[nt] = ((const s16x8*)Bs)[quad * 128 + wn * 64 + nt * 16 + l15];
#pragma unroll
    for (int mt = 0; mt < 4; ++mt)
#pragma unroll
      for (int nt = 0; nt < 4; ++nt)
        acc[mt][nt] =
            __builtin_amdgcn_mfma_f32_16x16x32_bf16(a[mt], b[nt], acc[mt][nt], 0, 0, 0);
    __syncthreads();
  }

#pragma unroll
  for (int mt = 0; mt < 4; ++mt) {
    const int gr0 = mb * 128 + wm * 64 + mt * 16 + quad * 4;
#pragma unroll
    for (int nt = 0; nt < 4; ++nt) {
      const int gc = nb * 128 + wn * 64 + nt * 16 + l15;
      const int g = gc >> 10, jg = gc & 1023;
      const float bb = bias[gc];
#pragma unroll
      for (int r2 = 0; r2 < 4; ++r2) {
        const int gr = gr0 + r2;
        const int bi = gr >> 9, s = gr & 511;   // row = b*512 + s
        xW[(size_t)((g * 512 + s) * 64 + bi) * 1024 + jg] = f2bf(acc[mt][nt][r2] + bb);
      }
    }
  }
}

// ---------------- K2-legacy (ws too small for Xsw) ----------------
__global__ __launch_bounds__(256) void k_gemm_legacy(const float* __restrict__ x,
                                                     const unsigned short* __restrict__ Wsw,
                                                     const float* __restrict__ bias,
                                                     unsigned short* __restrict__ xW) {
  __shared__ __align__(16) short As[4096];
  __shared__ __align__(16) short Bs[4096];
  const int nb = blockIdx.x;
  const int mb = blockIdx.y;
  const int tid = threadIdx.x;
  const int w = tid >> 6, lane = tid & 63;
  const int wm = w >> 1, wn = w & 1;
  const int quad = lane >> 4, l15 = lane & 15;

  f32x4 acc[4][4];
#pragma unroll
  for (int mt = 0; mt < 4; ++mt)
#pragma unroll
    for (int nt = 0; nt < 4; ++nt) acc[mt][nt] = (f32x4){0.f, 0.f, 0.f, 0.f};

  const int r = tid >> 1, half = tid & 1;
  const float* xrow = x + (size_t)(mb * 128 + r) * 1024 + half * 16;
  const u32x4* wsrc = (const u32x4*)Wsw;
  u32x4* bdst = (u32x4*)Bs;
  s16x8* asv = (s16x8*)As;

  for (int kb = 0; kb < 32; ++kb) {
    f32x4 v0 = *(const f32x4*)(xrow + kb * 32);
    f32x4 v1 = *(const f32x4*)(xrow + kb * 32 + 4);
    f32x4 v2 = *(const f32x4*)(xrow + kb * 32 + 8);
    f32x4 v3 = *(const f32x4*)(xrow + kb * 32 + 12);
    s16x8 s0, s1;
    s0[0] = (short)f2bf(v0[0]); s0[1] = (short)f2bf(v0[1]);
    s0[2] = (short)f2bf(v0[2]); s0[3] = (short)f2bf(v0[3]);
    s0[4] = (short)f2bf(v1[0]); s0[5] = (short)f2bf(v1[1]);
    s0[6] = (short)f2bf(v1[2]); s0[7] = (short)f2bf(v1[3]);
    s1[0] = (short)f2bf(v2[0]); s1[1] = (short)f2bf(v2[1]);
    s1[2] = (short)f2bf(v2[2]); s1[3] = (short)f2bf(v2[3]);
    s1[4] = (short)f2bf(v3[0]); s1[5] = (short)f2bf(v3[1]);
    s1[6] = (short)f2bf(v3[2]); s1[7] = (short)f2bf(v3[3]);
    asv[(half * 2 + 0) * 128 + r] = s0;
    asv[(half * 2 + 1) * 128 + r] = s1;
    const u32x4* bsrc = wsrc + (size_t)(kb * 32 + nb) * 512;
    bdst[tid] = bsrc[tid];
    bdst[tid + 256] = bsrc[tid + 256];
    __syncthreads();

    s16x8 a[4], b[4];
#pragma unroll
    for (int mt = 0; mt < 4; ++mt)
      a[mt] = ((const s16x8*)As)[quad * 128 + wm * 64 + mt * 16 + l15];
#pragma unroll
    for (int nt = 0; nt < 4; ++nt)
      b[nt] = ((const s16x8*)Bs)[quad * 128 + wn * 64 + nt * 16 + l15];
#pragma unroll
    for (int mt = 0; mt < 4; ++mt)
#pragma unroll
      for (int nt = 0; nt < 4; ++nt)
        acc[mt][nt] =
            __builtin_amdgcn_mfma_f32_16x16x32_bf16(a[mt], b[nt], acc[mt][nt], 0, 0, 0);
    __syncthreads();
  }

#pragma unroll
  for (int mt = 0; mt < 4; ++mt) {
    const int gr0 = mb * 128 + wm * 64 + mt * 16 + quad * 4;
#pragma unroll
    for (int nt = 0; nt < 4; ++nt) {
      const int gc = nb * 128 + wn * 64 + nt * 16 + l15;
      const int g = gc >> 10, jg = gc & 1023;
      const float bb = bias[gc];
#pragma unroll
      for (int r2 = 0; r2 < 4; ++r2) {
        const int gr = gr0 + r2;
        const int bi = gr >> 9, s = gr & 511;
        xW[(size_t)((g * 512 + s) * 64 + bi) * 1024 + jg] = f2bf(acc[mt][nt][r2] + bb);
      }
    }
  }
}

// ---------------- K3: persistent scan, tag-in-data sync ----------------
// hbuf (u32): [parity][mi=4][kbg=32][lane=64][i=8]; entry = bf16(h)<<16 | tag,
// tag = t+1 for h produced at step t (parity t&1). 65536 u32 per parity.
// Consumer at step t reads parity (t-1)&1 expecting tag == t; tags there are
// provably <= t, so per-group min(tag)==t <=> group fresh. Double-buffer +
// exact-match makes overwrite safe; per-dword store visibility carries
// value+tag atomically: no fences, no flags, no producer drain.
//
// Address group G (G=0..3) = hb_r_base + G*4096B = kbg {w*8+2G, w*8+2G+1}
// = 4 producer wgs. Issue blocks "=&v" early-clobber; single wait block
// binds all q "+v" with vmcnt(0) (waits everything incl. the xW prefetch
// at top-of-step — deliberate: that latency is the backoff that lets
// producer stores land before the first sample; round-4 proved removing
// it costs ~300us). Retries re-issue ONLY stale groups (4KB not 16KB).
#define HISSUE_G(G, PAR)                                                       \
  {                                                                            \
    const unsigned* bp_ = hbuf + (size_t)(PAR)*65536 + hb_r_base + (G)*1024;   \
    u64 a_ = (u64)(uintptr_t)bp_;                                              \
    asm volatile("global_load_dwordx4 %0, %4, off sc0 sc1\n\t"                 \
                 "global_load_dwordx4 %1, %4, off offset:16 sc0 sc1\n\t"       \
                 "global_load_dwordx4 %2, %4, off offset:2048 sc0 sc1\n\t"     \
                 "global_load_dwordx4 %3, %4, off offset:2064 sc0 sc1"         \
                 : "=&v"(q[4 * (G)]), "=&v"(q[4 * (G) + 1]),                   \
                   "=&v"(q[4 * (G) + 2]), "=&v"(q[4 * (G) + 3])                \
                 : "v"(a_)                                                     \
                 : "memory");                                                  \
  }

#define HWAIT()                                                                \
  asm volatile("s_waitcnt vmcnt(0)"                                            \
               : "+v"(q[0]), "+v"(q[1]), "+v"(q[2]), "+v"(q[3]), "+v"(q[4]),   \
                 "+v"(q[5]), "+v"(q[6]), "+v"(q[7]), "+v"(q[8]), "+v"(q[9]),   \
                 "+v"(q[10]), "+v"(q[11]), "+v"(q[12]), "+v"(q[13]),           \
                 "+v"(q[14]), "+v"(q[15])::"memory");

__global__ __launch_bounds__(256, 1) void k_scan(const float* __restrict__ U,
                                                 const unsigned short* __restrict__ xW,
                                                 unsigned* hbuf,
                                                 float* __restrict__ out) {
  __shared__ __align__(16) float P[10240];   // [par=2][w*4+g=16][j=16][b=20pad]

  const int wg = blockIdx.x;
  const int mi = wg >> 6, ni = wg & 63;
  const int tid = threadIdx.x;
  const int w = tid >> 6, lane = tid & 63;
  const int quad = lane >> 4, l15 = lane & 15;
  const int b_loc = tid >> 4, j_loc = tid & 15;

  // ---- load U fragments into registers (one-time) ----
  s16x8 uf[4][8];
  {
    const int cbase = ni * 16 + l15;
#pragma unroll
    for (int g = 0; g < 4; ++g) {
#pragma unroll
      for (int kb = 0; kb < 8; ++kb) {
        const int k0 = w * 256 + kb * 32 + quad * 8;
        s16x8 v;
#pragma unroll
        for (int i = 0; i < 8; ++i)
          v[i] = (short)f2bf(U[(size_t)(k0 + i) * 4096 + g * 1024 + cbase]);
        uf[g][kb] = v;
      }
    }
  }

  const int bg = mi * 16 + b_loc;             // global batch
  const int jg = ni * 16 + j_loc;             // global hidden unit
  const size_t hb_w_off =
      (size_t)((mi * 32 + (jg >> 5)) * 64 + ((jg >> 3) & 3) * 16 + b_loc) * 8 + (jg & 7);
  const size_t hb_r_base = (size_t)mi * 16384 + (size_t)w * 4096 + (size_t)lane * 8;
  float c = 0.f;

  for (int t = 0; t < S_LEN; ++t) {
    // prefetch xW for this (t, b, j): 4 gates (xW immutable -> plain loads).
    // These HBM loads retire inside the poll's first vmcnt(0) — deliberate.
    unsigned short xwv[4];
#pragma unroll
    for (int g = 0; g < 4; ++g)
      xwv[g] = xW[(size_t)((g * 512 + t) * 64 + bg) * 1024 + jg];

    float gate[4];
    const int par = (t & 1) * 16;
    if (t > 0) {
      u32x4 q[16];
      const int rpar = (t & 1) ^ 1;
      // initial issue: all 4 groups (16 loads), one wait
      HISSUE_G(0, rpar) HISSUE_G(1, rpar) HISSUE_G(2, rpar) HISSUE_G(3, rpar)
      HWAIT()
      // selective per-group retry
      for (;;) {
        unsigned sm = 0;
#pragma unroll
        for (int g2 = 0; g2 < 4; ++g2) {
          u16x2 mn = (u16x2){0xFFFFu, 0xFFFFu};
#pragma unroll
          for (int i = 0; i < 4; ++i)
#pragma unroll
            for (int j = 0; j < 4; ++j)
              mn = __builtin_elementwise_min(
                  mn, __builtin_bit_cast(u16x2, q[g2 * 4 + i][j]));
          if (__any((int)((unsigned)mn[0] != (unsigned)t))) sm |= (1u << g2);
        }
        if (!sm) break;
        if (sm & 1u) HISSUE_G(0, rpar)
        if (sm & 2u) HISSUE_G(1, rpar)
        if (sm & 4u) HISSUE_G(2, rpar)
        if (sm & 8u) HISSUE_G(3, rpar)
        HWAIT()
      }

      f32x4 acc[4];
#pragma unroll
      for (int g = 0; g < 4; ++g) acc[g] = (f32x4){0.f, 0.f, 0.f, 0.f};
#pragma unroll
      for (int kb = 0; kb < 8; ++kb) {
        u32x4 fw;
        fw[0] = __builtin_amdgcn_perm(q[2 * kb][1], q[2 * kb][0], 0x07060302u);
        fw[1] = __builtin_amdgcn_perm(q[2 * kb][3], q[2 * kb][2], 0x07060302u);
        fw[2] = __builtin_amdgcn_perm(q[2 * kb + 1][1], q[2 * kb + 1][0], 0x07060302u);
        fw[3] = __builtin_amdgcn_perm(q[2 * kb + 1][3], q[2 * kb + 1][2], 0x07060302u);
        s16x8 a = __builtin_bit_cast(s16x8, fw);
#pragma unroll
        for (int g = 0; g < 4; ++g)
          acc[g] = __builtin_amdgcn_mfma_f32_16x16x32_bf16(a, uf[g][kb], acc[g], 0, 0, 0);
      }
#pragma unroll
      for (int g = 0; g < 4; ++g) {
        float* dp = &P[(size_t)((par + w * 4 + g) * 16 + l15) * 20 + quad * 4];
        *(f32x4*)dp = acc[g];
      }
      __syncthreads();   // the ONLY barrier: P ready for cross-wave reduce
#pragma unroll
      for (int g = 0; g < 4; ++g) {
        float s = bf2f(xwv[g]);
#pragma unroll
        for (int w2 = 0; w2 < 4; ++w2)
          s += P[(size_t)((par + w2 * 4 + g) * 16 + j_loc) * 20 + b_loc];
        gate[g] = s;
      }
    } else {
#pragma unroll
      for (int g = 0; g < 4; ++g) gate[g] = bf2f(xwv[g]);
    }

    const float it = sigm(gate[0]);
    const float ft = sigm(gate[1]);
    const float gt = tanh_(gate[2]);
    const float ot = sigm(gate[3]);
    c = ft * c + it * gt;
    const float h = ot * tanh_(c);

    // tagged h store (value+tag in one dword -> atomic visibility, no fence).
    // Issued AFTER the P-read (reduce): certifies "h_t ready" AND "my
    // tile-(t-1) consumption done". Dead at t=511 -> skipped.
    if (t + 1 < S_LEN) {
      const unsigned tagged = ((unsigned)f2bf(h) << 16) | (unsigned)(t + 1);
      __hip_atomic_store(hbuf + (size_t)(t & 1) * 65536 + hb_w_off, tagged,
                         __ATOMIC_RELAXED, __HIP_MEMORY_SCOPE_AGENT);
    }

    out[(size_t)bg * (S_LEN * 1024) + (size_t)t * 1024 + jg] = h;
    if (t == S_LEN - 1) {
      out[HID + (size_t)bg * 1024 + jg] = h;                 // h_t
      out[HID + 65536 + (size_t)bg * 1024 + jg] = c;         // c_t
    }
  }
}

// ---------------- launch ----------------
extern "C" void kernel_launch(void* const* d_in, const int* in_sizes, int n_in,
                              void* d_out, int out_size, void* d_ws, size_t ws_size,
                              hipStream_t stream) {
  const float* x = (const float*)d_in[0];     // [64,512,1024]
  const float* W = (const float*)d_in[1];     // [1024,4096]
  const float* U = (const float*)d_in[2];     // [1024,4096]
  const float* bias = (const float*)d_in[3];  // [4096]
  float* out = (float*)d_out;
  char* ws = (char*)d_ws;

  // ws layout:
  unsigned* hbuf = (unsigned*)ws;                                    // 512 KB
  unsigned short* Wsw = (unsigned short*)(ws + 524288);              // 8 MB
  unsigned short* xW = (unsigned short*)(ws + 524288 + 8388608);     // 256 MB
  const size_t base = 524288 + 8388608 + 268435456;
  unsigned short* Xsw = (unsigned short*)(ws + base);                // 64 MB

  hipMemsetAsync(ws, 0, 524288, stream);   // zero hbuf (tag 0 everywhere)

  hipLaunchKernelGGL(k_convW, dim3(16384), dim3(256), 0, stream, W, Wsw);
  if (ws_size >= base + 67108864ULL) {
    hipLaunchKernelGGL(k_convX, dim3(16384), dim3(256), 0, stream, x, Xsw);
    hipLaunchKernelGGL(k_gemm, dim3(32, 256), dim3(256), 0, stream, Xsw, Wsw, bias, xW);
  } else {
    hipLaunchKernelGGL(k_gemm_legacy, dim3(32, 256), dim3(256), 0, stream, x, Wsw, bias,
                       xW);
  }
  hipLaunchKernelGGL(k_scan, dim3(256), dim3(256), 0, stream, U, xW, hbuf, out);
}